// Round 2
// baseline (1693.568 us; speedup 1.0000x reference)
//
#include <hip/hip_runtime.h>
#include <hip/hip_bf16.h>

#define TT 64
#define BB 4096
#define HH 256
#define BMb 16             // batches per block
#define NBLK (BB / BMb)    // 256 blocks -> 1 block/CU, 16 waves (4/SIMD)

typedef short bf16x8_t __attribute__((ext_vector_type(8)));
typedef float f32x4_t  __attribute__((ext_vector_type(4)));

// d_ws layout (byte offsets)
#define WS_WA_B   0u          // split bf16 weights: 2 layers*3 parts*8kt*16nt*64lane*8j shorts = 768 KB
#define WS_EMB_B  786432u     // emb f32
#define WS_REC_B  1048576u    // rec f32 [T][B][4], 4 MB

__device__ __forceinline__ float clip01f(float v) {
    return fminf(fmaxf(v, 0.0f), 1.0f);
}

__global__ __launch_bounds__(64) void setup_emb_kernel(float* __restrict__ emb) {
    int i = threadIdx.x;
    const double sigma = 64.0 / 10.0;
    const double c = 32.0;
    double d = ((double)i - c) / sigma;
    double e = exp(-0.5 * (d * d));
    double d0 = (0.0 - c) / sigma;
    double emin = exp(-0.5 * (d0 * d0));
    emb[i] = (float)((e - emin) / (1.0 - emin));
}

// Exact 3-way split w = hi + mid + lo into bf16 parts (residuals exact).
// Pre-swizzled to A-fragment order for mfma_f32_16x16x32_bf16:
// A[m=lane&15][k=(lane>>4)*8+j], flat = ((((layer*3+part)*8+kt)*16+ntile)*64+lane)*8+j
__global__ __launch_bounds__(256) void split_weights_kernel(
    const float* __restrict__ W_h, const float* __restrict__ W_h2,
    unsigned short* __restrict__ WA)
{
    int flat = blockIdx.x * 256 + threadIdx.x;     // < 393216
    int j     = flat & 7;
    int lane  = (flat >> 3) & 63;
    int ntile = (flat >> 9) & 15;
    int kt    = (flat >> 13) & 7;
    int rest  = flat >> 16;                        // 0..5
    int part  = rest % 3;
    int layer = rest / 3;
    int k = kt * 32 + (lane >> 4) * 8 + j;
    int n = ntile * 16 + (lane & 15);
    const float* W = layer ? W_h2 : W_h;           // row-major [n][k] = W[n*256+k]
    float w = W[n * HH + k];
    __hip_bfloat16 h = __float2bfloat16(w);
    float r1 = w - __bfloat162float(h);
    __hip_bfloat16 m = __float2bfloat16(r1);
    float r2 = r1 - __bfloat162float(m);
    __hip_bfloat16 l = __float2bfloat16(r2);
    __hip_bfloat16 v = (part == 0) ? h : ((part == 1) ? m : l);
    WA[flat] = *reinterpret_cast<unsigned short*>(&v);
}

union U16x8 { uint4 u; bf16x8_t v; };

// ---- named-register rolling prefetch (rule #20: NO arrays, every slot is a ----
// ---- distinct variable; all indices compile-time constants)                ----
// Slot p{kt%4}{a,b,c} holds A-frag uint4 of (kt, part 0/1/2).
// PHASE_STEP consumes slot, issues refill load (Wr, ktr), does 3 MFMAs in
// part-order 0,1,2 -> SAME accumulation order as baseline -> bit-identical D.
#define PHASE_STEP(pa, pb, pc, Wr, ktr, Bp, ktb, D) do {                       \
    U16x8 br_; br_.u = (Bp)[(ktb) * 64];            /* ds_read_b128 spikes */  \
    U16x8 a0_, a1_, a2_;                                                       \
    a0_.u = pa; a1_.u = pb; a2_.u = pc;                                        \
    pa = (Wr)[(0 * 8 + (ktr)) * 1024];                                         \
    pb = (Wr)[(1 * 8 + (ktr)) * 1024];                                         \
    pc = (Wr)[(2 * 8 + (ktr)) * 1024];                                         \
    D = __builtin_amdgcn_mfma_f32_16x16x32_bf16(a0_.v, br_.v, D, 0, 0, 0);     \
    D = __builtin_amdgcn_mfma_f32_16x16x32_bf16(a1_.v, br_.v, D, 0, 0, 0);     \
    D = __builtin_amdgcn_mfma_f32_16x16x32_bf16(a2_.v, br_.v, D, 0, 0, 0);     \
} while (0)

// One layer phase: kt = 0..7 ascending. Enters with slots = this phase kt0..3
// (issued >= one phase earlier); steps 0..3 refill kt4..7, steps 4..7 refill
// NEXT phase's kt0..3 -> the __syncthreads vmcnt drain only sees old loads.
#define MFMA_PHASE(Wcur, Wnext, Bp, D) do {                                    \
    PHASE_STEP(p0a, p0b, p0c, Wcur, 4, Bp, 0, D);                              \
    PHASE_STEP(p1a, p1b, p1c, Wcur, 5, Bp, 1, D);                              \
    PHASE_STEP(p2a, p2b, p2c, Wcur, 6, Bp, 2, D);                              \
    PHASE_STEP(p3a, p3b, p3c, Wcur, 7, Bp, 3, D);                              \
    PHASE_STEP(p0a, p0b, p0c, Wnext, 0, Bp, 4, D);                             \
    PHASE_STEP(p1a, p1b, p1c, Wnext, 1, Bp, 5, D);                             \
    PHASE_STEP(p2a, p2b, p2c, Wnext, 2, Bp, 6, D);                             \
    PHASE_STEP(p3a, p3b, p3c, Wnext, 3, Bp, 7, D);                             \
} while (0)

// Fill all 12 slots with kt0..3 (parts 0..2): slot = W[(part*8+kt)*1024]
#define PREFILL(W) do {                                                        \
    p0a = (W)[ 0 * 1024]; p0b = (W)[ 8 * 1024]; p0c = (W)[16 * 1024];          \
    p1a = (W)[ 1 * 1024]; p1b = (W)[ 9 * 1024]; p1c = (W)[17 * 1024];          \
    p2a = (W)[ 2 * 1024]; p2b = (W)[10 * 1024]; p2c = (W)[18 * 1024];          \
    p3a = (W)[ 3 * 1024]; p3b = (W)[11 * 1024]; p3c = (W)[19 * 1024];          \
} while (0)

// li_out walker for timestep t (wave 0 only). Ascending-k fmaf chain over
// S3F spikes (0.0/1.0): fmaf(1,w,p)=round(p+w), fmaf(0,w,p)=p -> bit-identical
// to the baseline select-add chain ("skip-zero == exact chain").
__device__ __forceinline__ void li_walker(
    const float* __restrict__ WoutS, const float (*__restrict__ S3F)[260],
    int wb, int ooc, float bto, float bo, float& m3s,
    float* __restrict__ rec, int t, int b0, int lane)
{
    if (lane < 32) {
        const float* wrow = WoutS + ooc * HH;
        const float* srow = S3F[wb];
        float p = 0.f;
#pragma unroll 8
        for (int k4 = 0; k4 < 64; ++k4) {
            float4 sv = *(const float4*)(srow + k4 * 4);
            float4 wv = *(const float4*)(wrow + k4 * 4);
            p = fmaf(sv.x, wv.x, p);
            p = fmaf(sv.y, wv.y, p);
            p = fmaf(sv.z, wv.z, p);
            p = fmaf(sv.w, wv.w, p);
        }
        float mm3 = fmaf(bto, m3s, p);
        mm3 = mm3 + bo;
        m3s = mm3;
        float spk = ((m3s - 1.0f) > 0.f) ? 1.f : 0.f;
        float om3 = __shfl_xor(m3s, 16, 64);
        float osp = __shfl_xor(spk, 16, 64);
        if (lane < 16) {
            *(float4*)(rec + ((size_t)t * BB + b0 + wb) * 4) =
                make_float4(spk, osp, m3s, om3);
        }
    }
}

__global__ __launch_bounds__(1024, 4) void snn_main_kernel(
    const float* __restrict__ x,
    const float* __restrict__ W_in, const float* __restrict__ b_in,
    const float* __restrict__ beta_in, const float* __restrict__ thr_in,
    const float* __restrict__ b_h, const float* __restrict__ beta_h, const float* __restrict__ thr_h,
    const float* __restrict__ b_h2, const float* __restrict__ beta_h2, const float* __restrict__ thr_h2,
    const float* __restrict__ W_out, const float* __restrict__ b_out, const float* __restrict__ beta_out,
    const unsigned short* __restrict__ WA, const float* __restrict__ emb,
    float* __restrict__ rec)
{
#pragma clang fp contract(off)   // all contraction EXPLICIT via fmaf
    const int tid = threadIdx.x;
    const int w = tid >> 6;       // wave 0..15 = n-tile
    const int lane = tid & 63;
    const int b = lane & 15;      // batch column (D col = lane&15)
    const int g = lane >> 4;      // row group   (D row = g*4+reg)
    const int b0 = blockIdx.x * BMb;

    __shared__ unsigned short sbuf1[8 * 64 * 8];            // B-frags spikes layer1 (8 KB)
    __shared__ unsigned short sbuf2[8 * 64 * 8];            // B-frags spikes layer2 (8 KB)
    __shared__ __align__(16) float S3F[16][260];            // layer-3 spikes [batch][n]
    __shared__ __align__(16) float WoutS[2 * HH];
    __shared__ float4 PL1a[HH];   // {wi0, wi1, wi2, b_in}
    __shared__ float2 PL1b[HH];   // {bt1c, th1}
    __shared__ float4 PL2[HH];    // {b_h,  bt2c, th2, -}
    __shared__ float4 PL3[HH];    // {b_h2, bt3c, th3, -}
    __shared__ float  xs[TT][BMb][3];   // staged x slice (12 KB)
    __shared__ float  embS[TT];

    if (tid < 512) WoutS[tid] = W_out[tid];
    if (tid < HH) {
        int n = tid;
        PL1a[n] = make_float4(W_in[n * 3], W_in[n * 3 + 1], W_in[n * 3 + 2], b_in[n]);
        PL1b[n] = make_float2(clip01f(beta_in[n]), thr_in[n]);
        PL2[n]  = make_float4(b_h[n],  clip01f(beta_h[n]),  thr_h[n],  0.f);
        PL3[n]  = make_float4(b_h2[n], clip01f(beta_h2[n]), thr_h2[n], 0.f);
    }
    if (tid < TT) embS[tid] = emb[tid];
    {   // 1024 threads = 64 t * 16 batches
        int ts = tid >> 4, bb = tid & 15;
        const float* xp = x + ((size_t)ts * BB + b0 + bb) * 3;
        xs[ts][bb][0] = xp[0];
        xs[ts][bb][1] = xp[1];
        xs[ts][bb][2] = xp[2];
    }

    // this thread's 4 neurons: n = w*16 + g*4 + r  (same as its D rows), batch b
    const int nb = w * 16 + g * 4;

    float m1[4], m2[4], m4[4];
#pragma unroll
    for (int r = 0; r < 4; ++r) { m1[r] = 0.f; m2[r] = 0.f; m4[r] = 0.f; }

    // spike -> B-frag LDS address (one b64 per thread):
    // k=n: kt2=w>>1, q=(w&1)*2+(g>>1), dst_lane=q*16+b, j0=(g&1)*4
    const int sb_off = (((w >> 1) * 64 + (((w & 1) * 2 + (g >> 1)) * 16 + b)) * 8 + (g & 1) * 4);

    // li_out walker state (wave 0, lanes 0..31): wb = batch, ooc = channel
    const int wb = lane & 15;
    const int ooc = (lane >> 4) & 1;
    float bto = clip01f(beta_out[ooc]);
    float bo = b_out[ooc];
    float m3s = 0.f;

    // A-fragment bases, pre-offset by this thread's (w, lane)
    const uint4* WL0 = (const uint4*)WA + (size_t)w * 64 + lane;        // layer-2 weights
    const uint4* WL1 = WL0 + 3 * 8 * 16 * 64;                           // layer-3 weights
    const uint4* Bp1 = (const uint4*)sbuf1 + lane;
    const uint4* Bp2 = (const uint4*)sbuf2 + lane;

    // 12 NAMED prefetch slots (48 VGPRs) — kt0..3 x parts 0..2 of next phase
    uint4 p0a, p0b, p0c, p1a, p1b, p1c, p2a, p2b, p2c, p3a, p3b, p3c;
    PREFILL(WL0);                 // t=0 layer-2 kt0..3 in flight before the loop

    __syncthreads();              // LDS init visible; prefill drains free here

    for (int t = 0; t < TT; ++t) {
        // ---- phase A: layer 1, exact f32 chain + contracted LIF; spikes -> B-frag LDS ----
        {
            float et = embS[t];
            float xe0 = xs[t][b][0] * et;
            float xe1 = xs[t][b][1] * et;
            float xe2 = xs[t][b][2] * et;
            unsigned sp[4];
#pragma unroll
            for (int r = 0; r < 4; ++r) {
                int n = nb + r;
                float4 pa = PL1a[n];
                float2 pb = PL1b[n];
                float a1 = xe0 * pa.x;
                a1 = fmaf(xe1, pa.y, a1);
                a1 = fmaf(xe2, pa.z, a1);
                float cur = a1 + pa.w;
                float rf = ((m1[r] - pb.y) > 0.f) ? 1.f : 0.f;   // reset from PREVIOUS mem
                float mm = fmaf(pb.x, m1[r], cur);               // contracted: beta*m + cur
                mm = fmaf(-rf, pb.y, mm);                        // contracted: - reset*thr
                m1[r] = mm;
                sp[r] = ((mm - pb.y) > 0.f) ? 0x3F80u : 0u;      // bf16 1.0 / 0.0
            }
            *(uint2*)(sbuf1 + sb_off) = make_uint2(sp[0] | (sp[1] << 16), sp[2] | (sp[3] << 16));
        }
        __syncthreads();   // BAR1

        // ---- phase B: wave0 runs walker(t-1) first (hides under others' MFMA/VMEM);
        //      then layer-2 MFMA with named-reg prefetched A; epilogue LIF ----
        if (w == 0 && t > 0)
            li_walker(WoutS, S3F, wb, ooc, bto, bo, m3s, rec, t - 1, b0, lane);
        {
            f32x4_t D = (f32x4_t){0.f, 0.f, 0.f, 0.f};
            MFMA_PHASE(WL0, WL1, Bp1, D);            // exits with slots = layer-3 kt0..3
            unsigned sp[4];
#pragma unroll
            for (int r = 0; r < 4; ++r) {
                int n = nb + r;
                float4 p2 = PL2[n];
                float cur = D[r] + p2.x;
                float rf = ((m2[r] - p2.z) > 0.f) ? 1.f : 0.f;
                float mm = fmaf(p2.y, m2[r], cur);
                mm = fmaf(-rf, p2.z, mm);
                m2[r] = mm;
                sp[r] = ((mm - p2.z) > 0.f) ? 0x3F80u : 0u;
            }
            *(uint2*)(sbuf2 + sb_off) = make_uint2(sp[0] | (sp[1] << 16), sp[2] | (sp[3] << 16));
        }
        __syncthreads();   // BAR2 (also fences walker's S3F reads vs next writes)

        // ---- phase C: layer-3 MFMA; epilogue LIF -> S3F spike floats ----
        {
            f32x4_t E = (f32x4_t){0.f, 0.f, 0.f, 0.f};
            MFMA_PHASE(WL1, WL0, Bp2, E);            // exits with slots = next-t layer-2 kt0..3
            float s3v[4];
#pragma unroll
            for (int r = 0; r < 4; ++r) {
                int n = nb + r;
                float4 p3 = PL3[n];
                float cur = E[r] + p3.x;
                float rf = ((m4[r] - p3.z) > 0.f) ? 1.f : 0.f;
                float mm = fmaf(p3.y, m4[r], cur);
                mm = fmaf(-rf, p3.z, mm);
                m4[r] = mm;
                s3v[r] = ((mm - p3.z) > 0.f) ? 1.0f : 0.0f;
            }
            *(float4*)(&S3F[b][nb]) = make_float4(s3v[0], s3v[1], s3v[2], s3v[3]);
        }
        __syncthreads();   // BAR3
    }

    // final walker for t = 63
    if (w == 0)
        li_walker(WoutS, S3F, wb, ooc, bto, bo, m3s, rec, TT - 1, b0, lane);
}

// out[r,o] = (ascending-k fma dot) + b_pred[o]
__global__ __launch_bounds__(256) void pred_kernel(
    const float* __restrict__ rec, const float* __restrict__ W_pred,
    const float* __restrict__ b_pred, float* __restrict__ out)
{
#pragma clang fp contract(off)
    int r = blockIdx.x * 256 + threadIdx.x;   // 0..4095
    const float* f = rec + (size_t)r * 256;
    float a0 = 0.f, a1 = 0.f;
#pragma unroll 4
    for (int c = 0; c < 256; ++c) {
        float v = f[c];
        a0 = fmaf(v, W_pred[c], a0);
        a1 = fmaf(v, W_pred[256 + c], a1);
    }
    out[r * 2 + 0] = a0 + b_pred[0];
    out[r * 2 + 1] = a1 + b_pred[1];
}

extern "C" void kernel_launch(void* const* d_in, const int* in_sizes, int n_in,
                              void* d_out, int out_size, void* d_ws, size_t ws_size,
                              hipStream_t stream)
{
    const float* x        = (const float*)d_in[0];
    const float* W_in     = (const float*)d_in[1];
    const float* b_in     = (const float*)d_in[2];
    const float* beta_in  = (const float*)d_in[3];
    const float* thr_in   = (const float*)d_in[4];
    const float* W_h      = (const float*)d_in[5];
    const float* b_h      = (const float*)d_in[6];
    const float* beta_h   = (const float*)d_in[7];
    const float* thr_h    = (const float*)d_in[8];
    const float* W_h2     = (const float*)d_in[9];
    const float* b_h2     = (const float*)d_in[10];
    const float* beta_h2  = (const float*)d_in[11];
    const float* thr_h2   = (const float*)d_in[12];
    const float* W_out    = (const float*)d_in[13];
    const float* b_out    = (const float*)d_in[14];
    const float* beta_out = (const float*)d_in[15];
    const float* W_pred   = (const float*)d_in[16];
    const float* b_pred   = (const float*)d_in[17];

    char* ws = (char*)d_ws;
    unsigned short* WA = (unsigned short*)(ws + WS_WA_B);
    float* emb = (float*)(ws + WS_EMB_B);
    float* rec = (float*)(ws + WS_REC_B);

    split_weights_kernel<<<1536, 256, 0, stream>>>(W_h, W_h2, WA);
    setup_emb_kernel<<<1, 64, 0, stream>>>(emb);

    snn_main_kernel<<<NBLK, 1024, 0, stream>>>(
        x, W_in, b_in, beta_in, thr_in,
        b_h, beta_h, thr_h,
        b_h2, beta_h2, thr_h2,
        W_out, b_out, beta_out,
        WA, emb, rec);

    pred_kernel<<<BB / 256, 256, 0, stream>>>(rec, W_pred, b_pred, (float*)d_out);
}

// Round 3
// 1677.026 us; speedup vs baseline: 1.0099x; 1.0099x over previous
//
#include <hip/hip_runtime.h>
#include <hip/hip_bf16.h>

#define TT 64
#define BB 4096
#define HH 256
#define BMb 16             // batches per block
#define NBLK (BB / BMb)    // 256 blocks -> 1 block/CU, 16 waves (4/SIMD)

typedef short bf16x8_t __attribute__((ext_vector_type(8)));
typedef float f32x4_t  __attribute__((ext_vector_type(4)));

// d_ws layout (byte offsets)
#define WS_WA_B   0u          // split bf16 weights: 2 layers*3 parts*8kt*16nt*64lane*8j shorts = 768 KB
#define WS_EMB_B  786432u     // emb f32
#define WS_REC_B  1048576u    // rec f32 [T][B][4], 4 MB

__device__ __forceinline__ float clip01f(float v) {
    return fminf(fmaxf(v, 0.0f), 1.0f);
}

__global__ __launch_bounds__(64) void setup_emb_kernel(float* __restrict__ emb) {
    int i = threadIdx.x;
    const double sigma = 64.0 / 10.0;
    const double c = 32.0;
    double d = ((double)i - c) / sigma;
    double e = exp(-0.5 * (d * d));
    double d0 = (0.0 - c) / sigma;
    double emin = exp(-0.5 * (d0 * d0));
    emb[i] = (float)((e - emin) / (1.0 - emin));
}

// Exact 3-way split w = hi + mid + lo into bf16 parts (residuals exact).
// Pre-swizzled to A-fragment order for mfma_f32_16x16x32_bf16:
// A[m=lane&15][k=(lane>>4)*8+j], flat = ((((layer*3+part)*8+kt)*16+ntile)*64+lane)*8+j
__global__ __launch_bounds__(256) void split_weights_kernel(
    const float* __restrict__ W_h, const float* __restrict__ W_h2,
    unsigned short* __restrict__ WA)
{
    int flat = blockIdx.x * 256 + threadIdx.x;     // < 393216
    int j     = flat & 7;
    int lane  = (flat >> 3) & 63;
    int ntile = (flat >> 9) & 15;
    int kt    = (flat >> 13) & 7;
    int rest  = flat >> 16;                        // 0..5
    int part  = rest % 3;
    int layer = rest / 3;
    int k = kt * 32 + (lane >> 4) * 8 + j;
    int n = ntile * 16 + (lane & 15);
    const float* W = layer ? W_h2 : W_h;           // row-major [n][k] = W[n*256+k]
    float w = W[n * HH + k];
    __hip_bfloat16 h = __float2bfloat16(w);
    float r1 = w - __bfloat162float(h);
    __hip_bfloat16 m = __float2bfloat16(r1);
    float r2 = r1 - __bfloat162float(m);
    __hip_bfloat16 l = __float2bfloat16(r2);
    __hip_bfloat16 v = (part == 0) ? h : ((part == 1) ? m : l);
    WA[flat] = *reinterpret_cast<unsigned short*>(&v);
}

union U16x8 { uint4 u; bf16x8_t v; };

// ---- named-register rolling prefetch (rule #20: NO arrays, every slot is a ----
// ---- distinct variable; all indices compile-time constants)                ----
// Slot p{kt%4}{a,b,c} holds A-frag uint4 of (kt, part 0/1/2).
// PHASE_STEP consumes slot, issues refill load (Wr, ktr), does 3 MFMAs in
// part-order 0,1,2 -> SAME accumulation order as baseline -> bit-identical D.
#define PHASE_STEP(pa, pb, pc, Wr, ktr, Bp, ktb, D) do {                       \
    U16x8 br_; br_.u = (Bp)[(ktb) * 64];            /* ds_read_b128 spikes */  \
    U16x8 a0_, a1_, a2_;                                                       \
    a0_.u = pa; a1_.u = pb; a2_.u = pc;                                        \
    pa = (Wr)[(0 * 8 + (ktr)) * 1024];                                         \
    pb = (Wr)[(1 * 8 + (ktr)) * 1024];                                         \
    pc = (Wr)[(2 * 8 + (ktr)) * 1024];                                         \
    D = __builtin_amdgcn_mfma_f32_16x16x32_bf16(a0_.v, br_.v, D, 0, 0, 0);     \
    D = __builtin_amdgcn_mfma_f32_16x16x32_bf16(a1_.v, br_.v, D, 0, 0, 0);     \
    D = __builtin_amdgcn_mfma_f32_16x16x32_bf16(a2_.v, br_.v, D, 0, 0, 0);     \
} while (0)

// One layer phase: kt = 0..7 ascending. Enters with slots = this phase kt0..3
// (issued >= one phase earlier); steps 0..3 refill kt4..7, steps 4..7 refill
// NEXT phase's kt0..3 -> the __syncthreads vmcnt drain only sees old loads.
#define MFMA_PHASE(Wcur, Wnext, Bp, D) do {                                    \
    PHASE_STEP(p0a, p0b, p0c, Wcur, 4, Bp, 0, D);                              \
    PHASE_STEP(p1a, p1b, p1c, Wcur, 5, Bp, 1, D);                              \
    PHASE_STEP(p2a, p2b, p2c, Wcur, 6, Bp, 2, D);                              \
    PHASE_STEP(p3a, p3b, p3c, Wcur, 7, Bp, 3, D);                              \
    PHASE_STEP(p0a, p0b, p0c, Wnext, 0, Bp, 4, D);                             \
    PHASE_STEP(p1a, p1b, p1c, Wnext, 1, Bp, 5, D);                             \
    PHASE_STEP(p2a, p2b, p2c, Wnext, 2, Bp, 6, D);                             \
    PHASE_STEP(p3a, p3b, p3c, Wnext, 3, Bp, 7, D);                             \
} while (0)

// Fill all 12 slots with kt0..3 (parts 0..2): slot = W[(part*8+kt)*1024]
#define PREFILL(W) do {                                                        \
    p0a = (W)[ 0 * 1024]; p0b = (W)[ 8 * 1024]; p0c = (W)[16 * 1024];          \
    p1a = (W)[ 1 * 1024]; p1b = (W)[ 9 * 1024]; p1c = (W)[17 * 1024];          \
    p2a = (W)[ 2 * 1024]; p2b = (W)[10 * 1024]; p2c = (W)[18 * 1024];          \
    p3a = (W)[ 3 * 1024]; p3b = (W)[11 * 1024]; p3c = (W)[19 * 1024];          \
} while (0)

// li_out walker for timestep t (wave 0 only). Ascending-k fmaf chain over
// S3F spikes (0.0/1.0): fmaf(1,w,p)=round(p+w), fmaf(0,w,p)=p -> bit-identical
// to the baseline select-add chain ("skip-zero == exact chain").
__device__ __forceinline__ void li_walker(
    const float* __restrict__ WoutS, const float (*__restrict__ S3F)[260],
    int wb, int ooc, float bto, float bo, float& m3s,
    float* __restrict__ rec, int t, int b0, int lane)
{
    if (lane < 32) {
        const float* wrow = WoutS + ooc * HH;
        const float* srow = S3F[wb];
        float p = 0.f;
#pragma unroll 8
        for (int k4 = 0; k4 < 64; ++k4) {
            float4 sv = *(const float4*)(srow + k4 * 4);
            float4 wv = *(const float4*)(wrow + k4 * 4);
            p = fmaf(sv.x, wv.x, p);
            p = fmaf(sv.y, wv.y, p);
            p = fmaf(sv.z, wv.z, p);
            p = fmaf(sv.w, wv.w, p);
        }
        float mm3 = fmaf(bto, m3s, p);
        mm3 = mm3 + bo;
        m3s = mm3;
        float spk = ((m3s - 1.0f) > 0.f) ? 1.f : 0.f;
        float om3 = __shfl_xor(m3s, 16, 64);
        float osp = __shfl_xor(spk, 16, 64);
        if (lane < 16) {
            *(float4*)(rec + ((size_t)t * BB + b0 + wb) * 4) =
                make_float4(spk, osp, m3s, om3);
        }
    }
}

// waves_per_eu PINNED at 4 (= 16 waves/block, 1 block/CU): VGPR budget 128, so the
// 12 uint4 prefetch slots (48 VGPRs) stay in registers. launch_bounds(1024,4) alone
// only sets MIN waves/EU; the allocator's 8-waves/EU occupancy heuristic then spilled
// the slots to scratch (R1/R2: VGPR=64, +184 MB scratch writes, L2 thrash -> 5.7 GB
// HBM fetch). Grid = 256 = 1 block/CU, so pinning costs nothing.
__attribute__((amdgpu_waves_per_eu(4, 4)))
__global__ __launch_bounds__(1024) void snn_main_kernel(
    const float* __restrict__ x,
    const float* __restrict__ W_in, const float* __restrict__ b_in,
    const float* __restrict__ beta_in, const float* __restrict__ thr_in,
    const float* __restrict__ b_h, const float* __restrict__ beta_h, const float* __restrict__ thr_h,
    const float* __restrict__ b_h2, const float* __restrict__ beta_h2, const float* __restrict__ thr_h2,
    const float* __restrict__ W_out, const float* __restrict__ b_out, const float* __restrict__ beta_out,
    const unsigned short* __restrict__ WA, const float* __restrict__ emb,
    float* __restrict__ rec)
{
#pragma clang fp contract(off)   // all contraction EXPLICIT via fmaf
    const int tid = threadIdx.x;
    const int w = tid >> 6;       // wave 0..15 = n-tile
    const int lane = tid & 63;
    const int b = lane & 15;      // batch column (D col = lane&15)
    const int g = lane >> 4;      // row group   (D row = g*4+reg)
    const int b0 = blockIdx.x * BMb;

    __shared__ unsigned short sbuf1[8 * 64 * 8];            // B-frags spikes layer1 (8 KB)
    __shared__ unsigned short sbuf2[8 * 64 * 8];            // B-frags spikes layer2 (8 KB)
    __shared__ __align__(16) float S3F[16][260];            // layer-3 spikes [batch][n]
    __shared__ __align__(16) float WoutS[2 * HH];
    __shared__ float4 PL1a[HH];   // {wi0, wi1, wi2, b_in}
    __shared__ float2 PL1b[HH];   // {bt1c, th1}
    __shared__ float4 PL2[HH];    // {b_h,  bt2c, th2, -}
    __shared__ float4 PL3[HH];    // {b_h2, bt3c, th3, -}
    __shared__ float  xs[TT][BMb][3];   // staged x slice (12 KB)
    __shared__ float  embS[TT];

    if (tid < 512) WoutS[tid] = W_out[tid];
    if (tid < HH) {
        int n = tid;
        PL1a[n] = make_float4(W_in[n * 3], W_in[n * 3 + 1], W_in[n * 3 + 2], b_in[n]);
        PL1b[n] = make_float2(clip01f(beta_in[n]), thr_in[n]);
        PL2[n]  = make_float4(b_h[n],  clip01f(beta_h[n]),  thr_h[n],  0.f);
        PL3[n]  = make_float4(b_h2[n], clip01f(beta_h2[n]), thr_h2[n], 0.f);
    }
    if (tid < TT) embS[tid] = emb[tid];
    {   // 1024 threads = 64 t * 16 batches
        int ts = tid >> 4, bb = tid & 15;
        const float* xp = x + ((size_t)ts * BB + b0 + bb) * 3;
        xs[ts][bb][0] = xp[0];
        xs[ts][bb][1] = xp[1];
        xs[ts][bb][2] = xp[2];
    }

    // this thread's 4 neurons: n = w*16 + g*4 + r  (same as its D rows), batch b
    const int nb = w * 16 + g * 4;

    float m1[4], m2[4], m4[4];
#pragma unroll
    for (int r = 0; r < 4; ++r) { m1[r] = 0.f; m2[r] = 0.f; m4[r] = 0.f; }

    // spike -> B-frag LDS address (one b64 per thread):
    // k=n: kt2=w>>1, q=(w&1)*2+(g>>1), dst_lane=q*16+b, j0=(g&1)*4
    const int sb_off = (((w >> 1) * 64 + (((w & 1) * 2 + (g >> 1)) * 16 + b)) * 8 + (g & 1) * 4);

    // li_out walker state (wave 0, lanes 0..31): wb = batch, ooc = channel
    const int wb = lane & 15;
    const int ooc = (lane >> 4) & 1;
    float bto = clip01f(beta_out[ooc]);
    float bo = b_out[ooc];
    float m3s = 0.f;

    // A-fragment bases, pre-offset by this thread's (w, lane)
    const uint4* WL0 = (const uint4*)WA + (size_t)w * 64 + lane;        // layer-2 weights
    const uint4* WL1 = WL0 + 3 * 8 * 16 * 64;                           // layer-3 weights
    const uint4* Bp1 = (const uint4*)sbuf1 + lane;
    const uint4* Bp2 = (const uint4*)sbuf2 + lane;

    // 12 NAMED prefetch slots (48 VGPRs) — kt0..3 x parts 0..2 of next phase
    uint4 p0a, p0b, p0c, p1a, p1b, p1c, p2a, p2b, p2c, p3a, p3b, p3c;
    PREFILL(WL0);                 // t=0 layer-2 kt0..3 in flight before the loop

    __syncthreads();              // LDS init visible; prefill drains free here

    for (int t = 0; t < TT; ++t) {
        // ---- phase A: layer 1, exact f32 chain + contracted LIF; spikes -> B-frag LDS ----
        {
            float et = embS[t];
            float xe0 = xs[t][b][0] * et;
            float xe1 = xs[t][b][1] * et;
            float xe2 = xs[t][b][2] * et;
            unsigned sp[4];
#pragma unroll
            for (int r = 0; r < 4; ++r) {
                int n = nb + r;
                float4 pa = PL1a[n];
                float2 pb = PL1b[n];
                float a1 = xe0 * pa.x;
                a1 = fmaf(xe1, pa.y, a1);
                a1 = fmaf(xe2, pa.z, a1);
                float cur = a1 + pa.w;
                float rf = ((m1[r] - pb.y) > 0.f) ? 1.f : 0.f;   // reset from PREVIOUS mem
                float mm = fmaf(pb.x, m1[r], cur);               // contracted: beta*m + cur
                mm = fmaf(-rf, pb.y, mm);                        // contracted: - reset*thr
                m1[r] = mm;
                sp[r] = ((mm - pb.y) > 0.f) ? 0x3F80u : 0u;      // bf16 1.0 / 0.0
            }
            *(uint2*)(sbuf1 + sb_off) = make_uint2(sp[0] | (sp[1] << 16), sp[2] | (sp[3] << 16));
        }
        __syncthreads();   // BAR1

        // ---- phase B: wave0 runs walker(t-1) first (hides under others' MFMA/VMEM);
        //      then layer-2 MFMA with named-reg prefetched A; epilogue LIF ----
        if (w == 0 && t > 0)
            li_walker(WoutS, S3F, wb, ooc, bto, bo, m3s, rec, t - 1, b0, lane);
        {
            f32x4_t D = (f32x4_t){0.f, 0.f, 0.f, 0.f};
            MFMA_PHASE(WL0, WL1, Bp1, D);            // exits with slots = layer-3 kt0..3
            unsigned sp[4];
#pragma unroll
            for (int r = 0; r < 4; ++r) {
                int n = nb + r;
                float4 p2 = PL2[n];
                float cur = D[r] + p2.x;
                float rf = ((m2[r] - p2.z) > 0.f) ? 1.f : 0.f;
                float mm = fmaf(p2.y, m2[r], cur);
                mm = fmaf(-rf, p2.z, mm);
                m2[r] = mm;
                sp[r] = ((mm - p2.z) > 0.f) ? 0x3F80u : 0u;
            }
            *(uint2*)(sbuf2 + sb_off) = make_uint2(sp[0] | (sp[1] << 16), sp[2] | (sp[3] << 16));
        }
        __syncthreads();   // BAR2 (also fences walker's S3F reads vs next writes)

        // ---- phase C: layer-3 MFMA; epilogue LIF -> S3F spike floats ----
        {
            f32x4_t E = (f32x4_t){0.f, 0.f, 0.f, 0.f};
            MFMA_PHASE(WL1, WL0, Bp2, E);            // exits with slots = next-t layer-2 kt0..3
            float s3v[4];
#pragma unroll
            for (int r = 0; r < 4; ++r) {
                int n = nb + r;
                float4 p3 = PL3[n];
                float cur = E[r] + p3.x;
                float rf = ((m4[r] - p3.z) > 0.f) ? 1.f : 0.f;
                float mm = fmaf(p3.y, m4[r], cur);
                mm = fmaf(-rf, p3.z, mm);
                m4[r] = mm;
                s3v[r] = ((mm - p3.z) > 0.f) ? 1.0f : 0.0f;
            }
            *(float4*)(&S3F[b][nb]) = make_float4(s3v[0], s3v[1], s3v[2], s3v[3]);
        }
        __syncthreads();   // BAR3
    }

    // final walker for t = 63
    if (w == 0)
        li_walker(WoutS, S3F, wb, ooc, bto, bo, m3s, rec, TT - 1, b0, lane);
}

// out[r,o] = (ascending-k fma dot) + b_pred[o]
__global__ __launch_bounds__(256) void pred_kernel(
    const float* __restrict__ rec, const float* __restrict__ W_pred,
    const float* __restrict__ b_pred, float* __restrict__ out)
{
#pragma clang fp contract(off)
    int r = blockIdx.x * 256 + threadIdx.x;   // 0..4095
    const float* f = rec + (size_t)r * 256;
    float a0 = 0.f, a1 = 0.f;
#pragma unroll 4
    for (int c = 0; c < 256; ++c) {
        float v = f[c];
        a0 = fmaf(v, W_pred[c], a0);
        a1 = fmaf(v, W_pred[256 + c], a1);
    }
    out[r * 2 + 0] = a0 + b_pred[0];
    out[r * 2 + 1] = a1 + b_pred[1];
}

extern "C" void kernel_launch(void* const* d_in, const int* in_sizes, int n_in,
                              void* d_out, int out_size, void* d_ws, size_t ws_size,
                              hipStream_t stream)
{
    const float* x        = (const float*)d_in[0];
    const float* W_in     = (const float*)d_in[1];
    const float* b_in     = (const float*)d_in[2];
    const float* beta_in  = (const float*)d_in[3];
    const float* thr_in   = (const float*)d_in[4];
    const float* W_h      = (const float*)d_in[5];
    const float* b_h      = (const float*)d_in[6];
    const float* beta_h   = (const float*)d_in[7];
    const float* thr_h    = (const float*)d_in[8];
    const float* W_h2     = (const float*)d_in[9];
    const float* b_h2     = (const float*)d_in[10];
    const float* beta_h2  = (const float*)d_in[11];
    const float* thr_h2   = (const float*)d_in[12];
    const float* W_out    = (const float*)d_in[13];
    const float* b_out    = (const float*)d_in[14];
    const float* beta_out = (const float*)d_in[15];
    const float* W_pred   = (const float*)d_in[16];
    const float* b_pred   = (const float*)d_in[17];

    char* ws = (char*)d_ws;
    unsigned short* WA = (unsigned short*)(ws + WS_WA_B);
    float* emb = (float*)(ws + WS_EMB_B);
    float* rec = (float*)(ws + WS_REC_B);

    split_weights_kernel<<<1536, 256, 0, stream>>>(W_h, W_h2, WA);
    setup_emb_kernel<<<1, 64, 0, stream>>>(emb);

    snn_main_kernel<<<NBLK, 1024, 0, stream>>>(
        x, W_in, b_in, beta_in, thr_in,
        b_h, beta_h, thr_h,
        b_h2, beta_h2, thr_h2,
        W_out, b_out, beta_out,
        WA, emb, rec);

    pred_kernel<<<BB / 256, 256, 0, stream>>>(rec, W_pred, b_pred, (float*)d_out);
}